// Round 1
// 567.860 us; speedup vs baseline: 1.3321x; 1.3321x over previous
//
#include <hip/hip_runtime.h>

typedef unsigned short u16;
typedef __attribute__((ext_vector_type(8))) short bf16x8;   // 8 bf16 = 4 VGPRs (MFMA A/B frag)
typedef __attribute__((ext_vector_type(4))) short bf16x4;
typedef __attribute__((ext_vector_type(4))) float f32x4;    // MFMA C/D frag

__device__ __forceinline__ float bf2f(u16 u){ union { unsigned int i; float f; } v; v.i = ((unsigned int)u) << 16; return v.f; }
__device__ __forceinline__ u16 f2bf(float f){ union { float f; unsigned int i; } v; v.f = f; unsigned int r = v.i + 0x7fffu + ((v.i >> 16) & 1u); return (u16)(r >> 16); }

#define MFMA(a,b,c) __builtin_amdgcn_mfma_f32_16x16x32_bf16((a),(b),(c),0,0,0)

// async global->LDS, 16B per lane. LDS dest is wave-uniform base + lane*16.
__device__ __forceinline__ void gl_lds16(const u16* g, u16* l){
  __builtin_amdgcn_global_load_lds((const __attribute__((address_space(1))) unsigned int*)g,
                                   (__attribute__((address_space(3))) unsigned int*)l, 16, 0, 0);
}

// ---------------- Kernel 1: GroupNorm stats (mean, rstd) per (b, group) ----------------
__global__ __launch_bounds__(256) void k_gn_stats(const float* __restrict__ x, float* __restrict__ stats){
  const int bg = blockIdx.x;                       // 0..511
  const float4* p = (const float4*)(x + (size_t)bg * 65536);
  const int tid = threadIdx.x;
  float s = 0.f, sq = 0.f;
  for (int i = 0; i < 64; ++i){
    float4 v = p[tid + i*256];
    s += v.x + v.y + v.z + v.w;
    sq += v.x*v.x + v.y*v.y + v.z*v.z + v.w*v.w;
  }
#pragma unroll
  for (int d = 32; d > 0; d >>= 1){ s += __shfl_down(s, d, 64); sq += __shfl_down(sq, d, 64); }
  __shared__ float ls[4], lq[4];
  if ((tid & 63) == 0){ ls[tid>>6] = s; lq[tid>>6] = sq; }
  __syncthreads();
  if (tid == 0){
    float S = ls[0]+ls[1]+ls[2]+ls[3];
    float Q = lq[0]+lq[1]+lq[2]+lq[3];
    float mean = S * (1.f/65536.f);
    float var  = Q * (1.f/65536.f) - mean*mean;
    stats[bg*2]   = mean;
    stats[bg*2+1] = rsqrtf(var + 1e-5f);
  }
}

// ---------------- Kernel 1b: convert f32 weights -> bf16 (w_qkv then w_proj, packed) ----------------
__global__ __launch_bounds__(256) void k_conv_w(const float* __restrict__ wq, const float* __restrict__ wp,
                                                u16* __restrict__ wout){
  const int base = (blockIdx.x*256 + threadIdx.x) * 4;       // 1024 blocks -> 1,048,576 elems
  float4 v;
  if (base < 786432) v = *(const float4*)(wq + base);
  else               v = *(const float4*)(wp + (base - 786432));
  bf16x4 o;
  o[0] = (short)f2bf(v.x); o[1] = (short)f2bf(v.y); o[2] = (short)f2bf(v.z); o[3] = (short)f2bf(v.w);
  *(bf16x4*)(wout + base) = o;
}

// ---------------- Kernel 2: GN affine + transpose -> Xnt[b][l][c] (bf16) ----------------
__global__ __launch_bounds__(256) void k_gn_t(const float* __restrict__ x, const float* __restrict__ stats,
                                              const float* __restrict__ gamma, const float* __restrict__ beta,
                                              u16* __restrict__ xnt){
  __shared__ u16 tile[64*72];                      // [c][l], stride 72
  const int l0 = blockIdx.x*64, c0 = blockIdx.y*64, b = blockIdx.z;
  const int tid = threadIdx.x;
#pragma unroll
  for (int i = 0; i < 2; ++i){
    int v = tid + i*256; int cc = v >> 3, seg = v & 7;
    int c = c0 + cc;
    float mu = stats[(b*32 + (c>>4))*2], rs = stats[(b*32 + (c>>4))*2 + 1];
    float ga = gamma[c] * rs;
    float be = beta[c] - mu * ga;                  // (x-mu)*rs*g + b = x*ga + be
    const float* px = x + ((size_t)(b*512 + c))*4096 + l0 + seg*8;
    float4 a0 = *(const float4*)px;
    float4 a1 = *(const float4*)(px + 4);
    bf16x8 ov;
    ov[0]=(short)f2bf(a0.x*ga+be); ov[1]=(short)f2bf(a0.y*ga+be);
    ov[2]=(short)f2bf(a0.z*ga+be); ov[3]=(short)f2bf(a0.w*ga+be);
    ov[4]=(short)f2bf(a1.x*ga+be); ov[5]=(short)f2bf(a1.y*ga+be);
    ov[6]=(short)f2bf(a1.z*ga+be); ov[7]=(short)f2bf(a1.w*ga+be);
    *(bf16x8*)&tile[cc*72 + seg*8] = ov;
  }
  __syncthreads();
#pragma unroll
  for (int i = 0; i < 2; ++i){
    int v = tid + i*256; int ll = v >> 3, seg = v & 7;
    bf16x8 ov;
#pragma unroll
    for (int j = 0; j < 8; ++j) ov[j] = (short)tile[(seg*8 + j)*72 + ll];
    *(bf16x8*)(xnt + ((size_t)(b*4096 + l0 + ll))*512 + c0 + seg*8) = ov;
  }
}

// ---------------- Kernel 3: QKV GEMM (m97-style: global_load_lds staging, swizzled LDS) ----------------
__global__ __launch_bounds__(256,2) void k_qkv(const u16* __restrict__ xnt, const u16* __restrict__ wq,
                                               const float* __restrict__ bq,
                                               u16* __restrict__ Qt, u16* __restrict__ Kt, u16* __restrict__ Vh){
  __shared__ u16 smem[17408];                      // 34816 B: sA[0:8192)+sW[8192:16384); epilogue reuses as 128x136
  u16* sA = smem;
  u16* sW = smem + 8192;
  const int l0 = blockIdx.x*128, o0 = blockIdx.y*128, b = blockIdx.z;
  const int tid = threadIdx.x, wv = tid>>6, lane = tid&63, g = lane>>4, r = lane&15;
  const int wm = wv>>1, wn = wv&1;
  const u16* Ab = xnt + ((size_t)(b*4096 + l0))*512;
  const u16* Wb = wq  + (size_t)o0*512;
  int srow[4], scol[4];
#pragma unroll
  for (int j = 0; j < 4; ++j){
    int s = wv*256 + j*64 + lane;
    srow[j] = s >> 3;
    scol[j] = ((s & 7) ^ (srow[j] & 7)) * 8;
  }
  f32x4 acc[4][4];
#pragma unroll
  for (int mt = 0; mt < 4; ++mt)
#pragma unroll
    for (int nt = 0; nt < 4; ++nt) acc[mt][nt] = (f32x4){0.f,0.f,0.f,0.f};

  const int key = r & 7;
  for (int c0 = 0; c0 < 512; c0 += 64){
    __syncthreads();                               // prev tile's reads done
#pragma unroll
    for (int j = 0; j < 4; ++j){
      u16* ldst = &smem[(wv*256 + j*64)*8];        // wave-uniform
      gl_lds16(Ab + (size_t)srow[j]*512 + c0 + scol[j], ldst);
      gl_lds16(Wb + (size_t)srow[j]*512 + c0 + scol[j], ldst + 8192);
    }
    __syncthreads();                               // staged data visible
#pragma unroll
    for (int half = 0; half < 2; ++half){
      bf16x8 a[4], w[4];
#pragma unroll
      for (int mt = 0; mt < 4; ++mt){ int R = wm*64 + mt*16 + r; a[mt] = *(const bf16x8*)&sA[(R*8 + ((half*4+g) ^ key))*8]; }
#pragma unroll
      for (int nt = 0; nt < 4; ++nt){ int R = wn*64 + nt*16 + r; w[nt] = *(const bf16x8*)&sW[(R*8 + ((half*4+g) ^ key))*8]; }
#pragma unroll
      for (int mt = 0; mt < 4; ++mt)
#pragma unroll
        for (int nt = 0; nt < 4; ++nt) acc[mt][nt] = MFMA(a[mt], w[nt], acc[mt][nt]);
    }
  }
  __syncthreads();                                 // last tile's reads done; reuse smem for epilogue
  const int t   = blockIdx.y >> 2;                 // 0=Q 1=K 2=V
  const int cp0 = (blockIdx.y & 3)*128;            // c' base within tensor
  const int h   = blockIdx.x >> 2;                 // head = l0/512
  const int lh0 = (blockIdx.x & 3)*128;            // pos base within head
#pragma unroll
  for (int nt = 0; nt < 4; ++nt){
    const int ol = wn*64 + nt*16 + r;              // o local (= c')
    const float bi = bq[o0 + ol];
#pragma unroll
    for (int mt = 0; mt < 4; ++mt){
      const int ll = wm*64 + mt*16 + g*4;          // l local (D rows, 4 consecutive)
      if (t == 2){                                 // V: LDS [o][l]
        bf16x4 pk;
#pragma unroll
        for (int rr = 0; rr < 4; ++rr) pk[rr] = (short)f2bf(acc[mt][nt][rr] + bi);
        *(bf16x4*)&smem[ol*136 + ll] = pk;
      } else {                                     // Q/K: LDS [l][o] (transpose)
#pragma unroll
        for (int rr = 0; rr < 4; ++rr) smem[(ll + rr)*136 + ol] = f2bf(acc[mt][nt][rr] + bi);
      }
    }
  }
  __syncthreads();
  const size_t bh = (size_t)(b*8 + h);
  u16* dst = (t == 0) ? Qt : Kt;
#pragma unroll
  for (int i = 0; i < 8; ++i){
    int v = tid + i*256; int row = v >> 4, seg = v & 15;
    bf16x8 d = *(const bf16x8*)&smem[row*136 + seg*8];
    if (t == 2){
      *(bf16x8*)(Vh + (bh*512 + cp0 + row)*512 + lh0 + seg*8) = d;      // Vh[b][h][c'][pos]
    } else {
      *(bf16x8*)(dst + (bh*512 + lh0 + row)*512 + cp0 + seg*8) = d;     // Qt/Kt[b][h][pos][c']
    }
  }
}

// ---------------- Kernel 4: fused attention, QBLK=128, 512 threads, 8 waves ----------------
// Phase 1 wave grid: wq in {0,1} (64 q rows), wk in {0..3} (128 k cols). acc 4x8 f32x4 = 128 VGPR.
// K[512][32]+Q[128][32] c-step tiles double-buffered in LDS (2 x 40KB) via global_load_lds,
// 16B chunks XOR-swizzled on the GLOBAL source side (chunk g stored at g^(row&3)) so linear
// LDS writes land swizzled -> conflict-free ds_read_b128 (8 lanes per 16B slot).
// P[128][512] bf16 lives in LDS (128KB, aliases dead staging buffers), chunk swizzle ch^(q&7).
// Phase 2: V streamed global->reg (per-wave-exclusive c-range 64), barrier-free k-loop.
// At aliases Qt in place: block reads only Q rows [q0,q0+128) and overwrites exactly those.
__global__ __launch_bounds__(512,2) void k_attn(const u16* __restrict__ Qt, const u16* __restrict__ Kt,
                                                const u16* __restrict__ Vh, u16* __restrict__ At){
  extern __shared__ __align__(16) u16 smem[];      // 135168 B dynamic
  float* sMax = (float*)(smem + 65536);            // byte 131072: [q 128][wk 4]
  float* sSum = sMax + 512;                        // byte 133120: [q 128][wk 4]
  const int q0 = blockIdx.x * 128;
  const int h = blockIdx.y, b = blockIdx.z;
  const int bh = b*8 + h;
  const int tid = threadIdx.x, wv = tid>>6, lane = tid&63, g = lane>>4, r = lane&15;
  const int wq = wv>>2, wk = wv&3;
  const size_t base = (size_t)bh * 262144;
  const u16* Qb = Qt + base + (size_t)q0*512;
  const u16* Kb = Kt + base;
  const u16* Vb = Vh + base;

  // staging: chunk i = wv*5+j covers rows [i*16,i*16+16) of stacked [Q(128 rows); K(512 rows)],
  // each row 64B = 4 x 16B chunks; lane L: row = i*16 + (L>>2), phys chunk = L&3,
  // logical c-chunk = (L&3) ^ (row&3)  (source-side pre-swizzle).
  const u16* gsrc[5];
  int ldoff[5];
  {
    const int l4 = lane >> 2, pc = lane & 3;
#pragma unroll
    for (int j = 0; j < 5; ++j){
      const int i = wv*5 + j;
      const int row = ((i < 8) ? (i*16) : ((i-8)*16)) + l4;
      const u16* bp = (i < 8) ? (Qb + (size_t)row*512) : (Kb + (size_t)row*512);
      gsrc[j] = bp + ((pc ^ (row & 3)) * 8);
      ldoff[j] = i * 512;                          // u16 units; Q at [0,4096), K at [4096,20480)
    }
  }

  f32x4 s[4][8];
#pragma unroll
  for (int mt = 0; mt < 4; ++mt)
#pragma unroll
    for (int nt = 0; nt < 8; ++nt) s[mt][nt] = (f32x4){0.f,0.f,0.f,0.f};

  const int qswz = (g ^ (r & 3)) * 8;              // swizzled 16B-chunk offset within 64B row (u16)

  // ---- Phase 1: S[q 128][k 512] = sum_c Q K^T, c-steps of 32, 2-phase prefetch
#pragma unroll
  for (int j = 0; j < 5; ++j) gl_lds16(gsrc[j], smem + ldoff[j]);     // stage cs=0 -> buf0
  __syncthreads();
  for (int cs = 0; cs < 16; ++cs){
    u16* bb = smem + (cs & 1) * 20480;
    if (cs < 15){
      u16* bn = smem + ((cs + 1) & 1) * 20480;
      const int c0 = (cs + 1) * 32;
#pragma unroll
      for (int j = 0; j < 5; ++j) gl_lds16(gsrc[j] + c0, bn + ldoff[j]);
    }
    bf16x8 a[4], kb[8];
#pragma unroll
    for (int mt = 0; mt < 4; ++mt) a[mt] = *(const bf16x8*)&bb[(wq*64 + mt*16 + r)*32 + qswz];
#pragma unroll
    for (int nt = 0; nt < 8; ++nt) kb[nt] = *(const bf16x8*)&bb[4096 + (wk*128 + nt*16 + r)*32 + qswz];
#pragma unroll
    for (int mt = 0; mt < 4; ++mt)
#pragma unroll
      for (int nt = 0; nt < 8; ++nt) s[mt][nt] = MFMA(a[mt], kb[nt], s[mt][nt]);
    __syncthreads();                               // drains vmcnt(0): next-tile stage complete
  }

  // ---- softmax over k=512 (D layout: q = wq*64+mt*16+g*4+rr, k = wk*128+nt*16+r)
#pragma unroll
  for (int mt = 0; mt < 4; ++mt)
#pragma unroll
    for (int nt = 0; nt < 8; ++nt)
#pragma unroll
      for (int rr = 0; rr < 4; ++rr) s[mt][nt][rr] *= 0.125f;

  float mx[4][4];
#pragma unroll
  for (int mt = 0; mt < 4; ++mt)
#pragma unroll
    for (int rr = 0; rr < 4; ++rr){
      float m = s[mt][0][rr];
#pragma unroll
      for (int nt = 1; nt < 8; ++nt) m = fmaxf(m, s[mt][nt][rr]);
      m = fmaxf(m, __shfl_xor(m, 1, 64)); m = fmaxf(m, __shfl_xor(m, 2, 64));
      m = fmaxf(m, __shfl_xor(m, 4, 64)); m = fmaxf(m, __shfl_xor(m, 8, 64));
      mx[mt][rr] = m;
    }
  if (r == 0){
#pragma unroll
    for (int mt = 0; mt < 4; ++mt)
#pragma unroll
      for (int rr = 0; rr < 4; ++rr) sMax[(wq*64 + mt*16 + g*4 + rr)*4 + wk] = mx[mt][rr];
  }
  __syncthreads();
#pragma unroll
  for (int mt = 0; mt < 4; ++mt)
#pragma unroll
    for (int rr = 0; rr < 4; ++rr){
      float4 v = *(const float4*)&sMax[(wq*64 + mt*16 + g*4 + rr)*4];
      mx[mt][rr] = fmaxf(fmaxf(v.x, v.y), fmaxf(v.z, v.w));
    }
  float inv[4][4];
#pragma unroll
  for (int mt = 0; mt < 4; ++mt)
#pragma unroll
    for (int rr = 0; rr < 4; ++rr){
      float t = 0.f;
#pragma unroll
      for (int nt = 0; nt < 8; ++nt){
        float e = __expf(s[mt][nt][rr] - mx[mt][rr]);
        s[mt][nt][rr] = e; t += e;
      }
      t += __shfl_xor(t, 1, 64); t += __shfl_xor(t, 2, 64);
      t += __shfl_xor(t, 4, 64); t += __shfl_xor(t, 8, 64);
      inv[mt][rr] = t;                             // wave-partial sum for now
    }
  if (r == 0){
#pragma unroll
    for (int mt = 0; mt < 4; ++mt)
#pragma unroll
      for (int rr = 0; rr < 4; ++rr) sSum[(wq*64 + mt*16 + g*4 + rr)*4 + wk] = inv[mt][rr];
  }
  __syncthreads();
#pragma unroll
  for (int mt = 0; mt < 4; ++mt)
#pragma unroll
    for (int rr = 0; rr < 4; ++rr){
      float4 v = *(const float4*)&sSum[(wq*64 + mt*16 + g*4 + rr)*4];
      inv[mt][rr] = 1.f / (v.x + v.y + v.z + v.w);
    }
  // write P (bf16, chunk-swizzled ch^(q&7)) over the dead staging region
  {
    const int kx7 = r & 7, kbase = wk*16 + (r>>3);
#pragma unroll
    for (int mt = 0; mt < 4; ++mt)
#pragma unroll
      for (int rr = 0; rr < 4; ++rr){
        const int q = wq*64 + mt*16 + g*4 + rr;
        const int ro = q*512, qx = q & 7;
        const float iv = inv[mt][rr];
#pragma unroll
        for (int nt = 0; nt < 8; ++nt){
          const int ch = kbase + nt*2;             // k>>3
          smem[ro + ((ch ^ qx) * 8) + kx7] = f2bf(s[mt][nt][rr] * iv);
        }
      }
  }
  __syncthreads();

  // ---- Phase 2: A[c 512][q 128] = sum_k V[c][k] P[q][k]; wave owns c-range 64, barrier-free
  f32x4 o[4][8];
#pragma unroll
  for (int mt = 0; mt < 4; ++mt)
#pragma unroll
    for (int nt = 0; nt < 8; ++nt) o[mt][nt] = (f32x4){0.f,0.f,0.f,0.f};
  const u16* Vw = Vb + (size_t)(wv*64 + r)*512 + g*8;
  bf16x8 vf[2][4];
#pragma unroll
  for (int mt = 0; mt < 4; ++mt) vf[0][mt] = *(const bf16x8*)(Vw + mt*8192);
#pragma unroll
  for (int kk = 0; kk < 16; ++kk){
    if (kk < 15){
#pragma unroll
      for (int mt = 0; mt < 4; ++mt) vf[(kk+1)&1][mt] = *(const bf16x8*)(Vw + mt*8192 + (kk+1)*32);
    }
    bf16x8 pp[8];
#pragma unroll
    for (int nt = 0; nt < 8; ++nt){
      const int q = nt*16 + r;
      pp[nt] = *(const bf16x8*)&smem[q*512 + (((kk*4 + g) ^ (r & 7)) * 8)];
    }
#pragma unroll
    for (int mt = 0; mt < 4; ++mt)
#pragma unroll
      for (int nt = 0; nt < 8; ++nt) o[mt][nt] = MFMA(vf[kk&1][mt], pp[nt], o[mt][nt]);
  }
  __syncthreads();                                 // all P reads done; reuse smem as At bounce

  // bounce o -> LDS [q][c] (same chunk swizzle), then coalesced copy out
#pragma unroll
  for (int mt = 0; mt < 4; ++mt){
    const int c = wv*64 + mt*16 + g*4;
    const int ch = c >> 3, cl = c & 7;
#pragma unroll
    for (int nt = 0; nt < 8; ++nt){
      const int q = nt*16 + r;
      bf16x4 pk;
#pragma unroll
      for (int rr = 0; rr < 4; ++rr) pk[rr] = (short)f2bf(o[mt][nt][rr]);
      *(bf16x4*)&smem[q*512 + ((ch ^ (r & 7)) * 8) + cl] = pk;
    }
  }
  __syncthreads();
  u16* Ad = At + ((size_t)(bh*512 + q0))*512;      // exactly this block's Q rows (in-place alias)
#pragma unroll
  for (int i = 0; i < 16; ++i){
    const int idx = tid + i*512, q = idx >> 6, ch = idx & 63;
    bf16x8 d = *(const bf16x8*)&smem[q*512 + ((ch ^ (q & 7)) * 8)];
    *(bf16x8*)(Ad + (size_t)q*512 + ch*8) = d;
  }
}

// ---------------- Kernel 5: proj GEMM (m97-style) + f32 residual -> f32 out ----------------
__global__ __launch_bounds__(256,2) void k_proj(const u16* __restrict__ At, const u16* __restrict__ wp,
                                                const float* __restrict__ bpr, const float* __restrict__ x,
                                                float* __restrict__ out){
  __shared__ u16 smem[17408];
  u16* sA = smem;
  u16* sW = smem + 8192;
  const int l0 = blockIdx.x*128, o0 = blockIdx.y*128, b = blockIdx.z;
  const int tid = threadIdx.x, wv = tid>>6, lane = tid&63, g = lane>>4, r = lane&15;
  const int wm = wv>>1, wn = wv&1;
  const u16* Ab = At + ((size_t)(b*4096 + l0))*512;
  const u16* Wb = wp + (size_t)o0*512;
  int srow[4], scol[4];
#pragma unroll
  for (int j = 0; j < 4; ++j){
    int s = wv*256 + j*64 + lane;
    srow[j] = s >> 3;
    scol[j] = ((s & 7) ^ (srow[j] & 7)) * 8;
  }
  f32x4 acc[4][4];
#pragma unroll
  for (int mt = 0; mt < 4; ++mt)
#pragma unroll
    for (int nt = 0; nt < 4; ++nt) acc[mt][nt] = (f32x4){0.f,0.f,0.f,0.f};
  const int key = r & 7;
  for (int c0 = 0; c0 < 512; c0 += 64){
    __syncthreads();
#pragma unroll
    for (int j = 0; j < 4; ++j){
      u16* ldst = &smem[(wv*256 + j*64)*8];
      gl_lds16(Ab + (size_t)srow[j]*512 + c0 + scol[j], ldst);
      gl_lds16(Wb + (size_t)srow[j]*512 + c0 + scol[j], ldst + 8192);
    }
    __syncthreads();
#pragma unroll
    for (int half = 0; half < 2; ++half){
      bf16x8 a[4], w[4];
#pragma unroll
      for (int mt = 0; mt < 4; ++mt){ int R = wm*64 + mt*16 + r; a[mt] = *(const bf16x8*)&sA[(R*8 + ((half*4+g) ^ key))*8]; }
#pragma unroll
      for (int nt = 0; nt < 4; ++nt){ int R = wn*64 + nt*16 + r; w[nt] = *(const bf16x8*)&sW[(R*8 + ((half*4+g) ^ key))*8]; }
#pragma unroll
      for (int mt = 0; mt < 4; ++mt)
#pragma unroll
        for (int nt = 0; nt < 4; ++nt) acc[mt][nt] = MFMA(a[mt], w[nt], acc[mt][nt]);
    }
  }
  __syncthreads();
#pragma unroll
  for (int nt = 0; nt < 4; ++nt){
    const int ol = wn*64 + nt*16 + r;
    const float bi = bpr[o0 + ol];
#pragma unroll
    for (int mt = 0; mt < 4; ++mt){
      const int ll = wm*64 + mt*16 + g*4;
      bf16x4 pk;
#pragma unroll
      for (int rr = 0; rr < 4; ++rr) pk[rr] = (short)f2bf(acc[mt][nt][rr] + bi);
      *(bf16x4*)&smem[ol*136 + ll] = pk;            // LDS [o][l]
    }
  }
  __syncthreads();
#pragma unroll
  for (int i = 0; i < 16; ++i){
    int v = tid + i*256; int row = v >> 5, seg = v & 31;   // row=o-local 0..127, seg*4 = l-local
    bf16x4 d = *(const bf16x4*)&smem[row*136 + seg*4];
    const size_t gi = ((size_t)(b*512 + o0 + row))*4096 + l0 + seg*4;
    float4 xv = *(const float4*)(x + gi);
    float4 ov;
    ov.x = bf2f((u16)d[0]) + xv.x;
    ov.y = bf2f((u16)d[1]) + xv.y;
    ov.z = bf2f((u16)d[2]) + xv.z;
    ov.w = bf2f((u16)d[3]) + xv.w;
    *(float4*)(out + gi) = ov;
  }
}

extern "C" void kernel_launch(void* const* d_in, const int* in_sizes, int n_in,
                              void* d_out, int out_size, void* d_ws, size_t ws_size,
                              hipStream_t stream) {
  (void)in_sizes; (void)n_in; (void)out_size; (void)ws_size;
  const float* x     = (const float*)d_in[0];
  const float* gamma = (const float*)d_in[1];
  const float* beta  = (const float*)d_in[2];
  const float* wqkv  = (const float*)d_in[3];
  const float* bqkv  = (const float*)d_in[4];
  const float* wproj = (const float*)d_in[5];
  const float* bproj = (const float*)d_in[6];
  float* out = (float*)d_out;
  char* ws = (char*)d_ws;

  float* stats = (float*)ws;                        // 8 KB
  u16* W16  = (u16*)(ws + 8192);                    // wqkv16 (786432) + wproj16 (262144)
  u16* Wq16 = W16;
  u16* Wp16 = W16 + 786432;
  u16* Qt = (u16*)(ws + 8192 + 2097152);            // 64 MiB  [b][h][pos][c]  (becomes At in place)
  u16* Kt = Qt + (size_t)33554432;                  // 64 MiB  [b][h][pos][c]
  u16* Vh = Kt + (size_t)33554432;                  // 64 MiB  [b][h][c][pos]
  u16* At = Qt;                                     // in-place alias (see k_attn)
  u16* Xnt = (u16*)d_out;                           // bf16 staging in d_out (dead before k_proj writes)

  static bool attn_attr = false;
  if (!attn_attr){
    hipFuncSetAttribute((const void*)k_attn, hipFuncAttributeMaxDynamicSharedMemorySize, 135168);
    attn_attr = true;
  }

  k_gn_stats<<<512, 256, 0, stream>>>(x, stats);
  k_conv_w<<<1024, 256, 0, stream>>>(wqkv, wproj, W16);
  k_gn_t<<<dim3(64,8,16), 256, 0, stream>>>(x, stats, gamma, beta, Xnt);
  k_qkv<<<dim3(32,12,16), 256, 0, stream>>>(Xnt, Wq16, bqkv, Qt, Kt, Vh);
  k_attn<<<dim3(4,8,16), 512, 135168, stream>>>(Qt, Kt, Vh, At);
  k_proj<<<dim3(32,4,16), 256, 0, stream>>>(At, Wp16, bproj, x, out);
}

// Round 2
// 545.688 us; speedup vs baseline: 1.3862x; 1.0406x over previous
//
#include <hip/hip_runtime.h>

typedef unsigned short u16;
typedef __attribute__((ext_vector_type(8))) short bf16x8;   // 8 bf16 = 4 VGPRs (MFMA A/B frag)
typedef __attribute__((ext_vector_type(4))) short bf16x4;
typedef __attribute__((ext_vector_type(4))) float f32x4;    // MFMA C/D frag

__device__ __forceinline__ float bf2f(u16 u){ union { unsigned int i; float f; } v; v.i = ((unsigned int)u) << 16; return v.f; }
__device__ __forceinline__ u16 f2bf(float f){ union { float f; unsigned int i; } v; v.f = f; unsigned int r = v.i + 0x7fffu + ((v.i >> 16) & 1u); return (u16)(r >> 16); }

#define MFMA(a,b,c) __builtin_amdgcn_mfma_f32_16x16x32_bf16((a),(b),(c),0,0,0)

// async global->LDS, 16B per lane. LDS dest is wave-uniform base + lane*16.
__device__ __forceinline__ void gl_lds16(const u16* g, u16* l){
  __builtin_amdgcn_global_load_lds((const __attribute__((address_space(1))) unsigned int*)g,
                                   (__attribute__((address_space(3))) unsigned int*)l, 16, 0, 0);
}

// ---------------- Kernel 1: GroupNorm stats (mean, rstd) per (b, group) ----------------
__global__ __launch_bounds__(256) void k_gn_stats(const float* __restrict__ x, float* __restrict__ stats){
  const int bg = blockIdx.x;                       // 0..511
  const float4* p = (const float4*)(x + (size_t)bg * 65536);
  const int tid = threadIdx.x;
  float s = 0.f, sq = 0.f;
  for (int i = 0; i < 64; ++i){
    float4 v = p[tid + i*256];
    s += v.x + v.y + v.z + v.w;
    sq += v.x*v.x + v.y*v.y + v.z*v.z + v.w*v.w;
  }
#pragma unroll
  for (int d = 32; d > 0; d >>= 1){ s += __shfl_down(s, d, 64); sq += __shfl_down(sq, d, 64); }
  __shared__ float ls[4], lq[4];
  if ((tid & 63) == 0){ ls[tid>>6] = s; lq[tid>>6] = sq; }
  __syncthreads();
  if (tid == 0){
    float S = ls[0]+ls[1]+ls[2]+ls[3];
    float Q = lq[0]+lq[1]+lq[2]+lq[3];
    float mean = S * (1.f/65536.f);
    float var  = Q * (1.f/65536.f) - mean*mean;
    stats[bg*2]   = mean;
    stats[bg*2+1] = rsqrtf(var + 1e-5f);
  }
}

// ---------------- Kernel 1b: convert f32 weights -> bf16 (w_qkv then w_proj, packed) ----------------
__global__ __launch_bounds__(256) void k_conv_w(const float* __restrict__ wq, const float* __restrict__ wp,
                                                u16* __restrict__ wout){
  const int base = (blockIdx.x*256 + threadIdx.x) * 4;       // 1024 blocks -> 1,048,576 elems
  float4 v;
  if (base < 786432) v = *(const float4*)(wq + base);
  else               v = *(const float4*)(wp + (base - 786432));
  bf16x4 o;
  o[0] = (short)f2bf(v.x); o[1] = (short)f2bf(v.y); o[2] = (short)f2bf(v.z); o[3] = (short)f2bf(v.w);
  *(bf16x4*)(wout + base) = o;
}

// ---------------- Kernel 2: GN affine + transpose -> Xnt[b][l][c] (bf16) ----------------
__global__ __launch_bounds__(256) void k_gn_t(const float* __restrict__ x, const float* __restrict__ stats,
                                              const float* __restrict__ gamma, const float* __restrict__ beta,
                                              u16* __restrict__ xnt){
  __shared__ u16 tile[64*72];                      // [c][l], stride 72
  const int l0 = blockIdx.x*64, c0 = blockIdx.y*64, b = blockIdx.z;
  const int tid = threadIdx.x;
#pragma unroll
  for (int i = 0; i < 2; ++i){
    int v = tid + i*256; int cc = v >> 3, seg = v & 7;
    int c = c0 + cc;
    float mu = stats[(b*32 + (c>>4))*2], rs = stats[(b*32 + (c>>4))*2 + 1];
    float ga = gamma[c] * rs;
    float be = beta[c] - mu * ga;                  // (x-mu)*rs*g + b = x*ga + be
    const float* px = x + ((size_t)(b*512 + c))*4096 + l0 + seg*8;
    float4 a0 = *(const float4*)px;
    float4 a1 = *(const float4*)(px + 4);
    bf16x8 ov;
    ov[0]=(short)f2bf(a0.x*ga+be); ov[1]=(short)f2bf(a0.y*ga+be);
    ov[2]=(short)f2bf(a0.z*ga+be); ov[3]=(short)f2bf(a0.w*ga+be);
    ov[4]=(short)f2bf(a1.x*ga+be); ov[5]=(short)f2bf(a1.y*ga+be);
    ov[6]=(short)f2bf(a1.z*ga+be); ov[7]=(short)f2bf(a1.w*ga+be);
    *(bf16x8*)&tile[cc*72 + seg*8] = ov;
  }
  __syncthreads();
#pragma unroll
  for (int i = 0; i < 2; ++i){
    int v = tid + i*256; int ll = v >> 3, seg = v & 7;
    bf16x8 ov;
#pragma unroll
    for (int j = 0; j < 8; ++j) ov[j] = (short)tile[(seg*8 + j)*72 + ll];
    *(bf16x8*)(xnt + ((size_t)(b*4096 + l0 + ll))*512 + c0 + seg*8) = ov;
  }
}

// ---------------- Kernel 3: QKV GEMM (m97-style: global_load_lds staging, swizzled LDS) ----------------
__global__ __launch_bounds__(256,2) void k_qkv(const u16* __restrict__ xnt, const u16* __restrict__ wq,
                                               const float* __restrict__ bq,
                                               u16* __restrict__ Qt, u16* __restrict__ Kt, u16* __restrict__ Vh){
  __shared__ u16 smem[17408];                      // 34816 B: sA[0:8192)+sW[8192:16384); epilogue reuses as 128x136
  u16* sA = smem;
  u16* sW = smem + 8192;
  const int l0 = blockIdx.x*128, o0 = blockIdx.y*128, b = blockIdx.z;
  const int tid = threadIdx.x, wv = tid>>6, lane = tid&63, g = lane>>4, r = lane&15;
  const int wm = wv>>1, wn = wv&1;
  const u16* Ab = xnt + ((size_t)(b*4096 + l0))*512;
  const u16* Wb = wq  + (size_t)o0*512;
  int srow[4], scol[4];
#pragma unroll
  for (int j = 0; j < 4; ++j){
    int s = wv*256 + j*64 + lane;
    srow[j] = s >> 3;
    scol[j] = ((s & 7) ^ (srow[j] & 7)) * 8;
  }
  f32x4 acc[4][4];
#pragma unroll
  for (int mt = 0; mt < 4; ++mt)
#pragma unroll
    for (int nt = 0; nt < 4; ++nt) acc[mt][nt] = (f32x4){0.f,0.f,0.f,0.f};

  const int key = r & 7;
  for (int c0 = 0; c0 < 512; c0 += 64){
    __syncthreads();                               // prev tile's reads done
#pragma unroll
    for (int j = 0; j < 4; ++j){
      u16* ldst = &smem[(wv*256 + j*64)*8];        // wave-uniform
      gl_lds16(Ab + (size_t)srow[j]*512 + c0 + scol[j], ldst);
      gl_lds16(Wb + (size_t)srow[j]*512 + c0 + scol[j], ldst + 8192);
    }
    __syncthreads();                               // staged data visible
#pragma unroll
    for (int half = 0; half < 2; ++half){
      bf16x8 a[4], w[4];
#pragma unroll
      for (int mt = 0; mt < 4; ++mt){ int R = wm*64 + mt*16 + r; a[mt] = *(const bf16x8*)&sA[(R*8 + ((half*4+g) ^ key))*8]; }
#pragma unroll
      for (int nt = 0; nt < 4; ++nt){ int R = wn*64 + nt*16 + r; w[nt] = *(const bf16x8*)&sW[(R*8 + ((half*4+g) ^ key))*8]; }
#pragma unroll
      for (int mt = 0; mt < 4; ++mt)
#pragma unroll
        for (int nt = 0; nt < 4; ++nt) acc[mt][nt] = MFMA(a[mt], w[nt], acc[mt][nt]);
    }
  }
  __syncthreads();                                 // last tile's reads done; reuse smem for epilogue
  const int t   = blockIdx.y >> 2;                 // 0=Q 1=K 2=V
  const int cp0 = (blockIdx.y & 3)*128;            // c' base within tensor
  const int h   = blockIdx.x >> 2;                 // head = l0/512
  const int lh0 = (blockIdx.x & 3)*128;            // pos base within head
#pragma unroll
  for (int nt = 0; nt < 4; ++nt){
    const int ol = wn*64 + nt*16 + r;              // o local (= c')
    const float bi = bq[o0 + ol];
#pragma unroll
    for (int mt = 0; mt < 4; ++mt){
      const int ll = wm*64 + mt*16 + g*4;          // l local (D rows, 4 consecutive)
      if (t == 2){                                 // V: LDS [o][l]
        bf16x4 pk;
#pragma unroll
        for (int rr = 0; rr < 4; ++rr) pk[rr] = (short)f2bf(acc[mt][nt][rr] + bi);
        *(bf16x4*)&smem[ol*136 + ll] = pk;
      } else {                                     // Q/K: LDS [l][o] (transpose)
#pragma unroll
        for (int rr = 0; rr < 4; ++rr) smem[(ll + rr)*136 + ol] = f2bf(acc[mt][nt][rr] + bi);
      }
    }
  }
  __syncthreads();
  const size_t bh = (size_t)(b*8 + h);
  u16* dst = (t == 0) ? Qt : Kt;
#pragma unroll
  for (int i = 0; i < 8; ++i){
    int v = tid + i*256; int row = v >> 4, seg = v & 15;
    bf16x8 d = *(const bf16x8*)&smem[row*136 + seg*8];
    if (t == 2){
      *(bf16x8*)(Vh + (bh*512 + cp0 + row)*512 + lh0 + seg*8) = d;      // Vh[b][h][c'][pos]
    } else {
      *(bf16x8*)(dst + (bh*512 + lh0 + row)*512 + cp0 + seg*8) = d;     // Qt/Kt[b][h][pos][c']
    }
  }
}

// ---------------- Kernel 4: fused attention, QBLK=128, 512 threads, 8 waves ----------------
// Grid: 1D 512, XCD-chunked swizzle so the 4 q-tiles of each (b,h) land on one XCD (K/V L2 reuse).
// Phase 1: K[512][32]+Q[128][32] c-step tiles in LDS, 3 buffers x 40KB, depth-2 prefetch with
// counted s_waitcnt vmcnt(5) + raw s_barrier (never drain to 0 in the loop). 16B chunks
// XOR-swizzled on the GLOBAL source side so linear global_load_lds writes land swizzled ->
// conflict-free ds_read_b128.
// P[128][512] bf16 lives in LDS (128KB, aliases dead staging buffers), chunk swizzle ch^(q&7).
// Phase 2: V streamed global->reg (per-wave-exclusive c-range 64), barrier-free k-loop; first
// V fragments issued before the softmax-exit barrier.
__global__ __launch_bounds__(512,2) void k_attn(const u16* __restrict__ Qt, const u16* __restrict__ Kt,
                                                const u16* __restrict__ Vh, u16* __restrict__ At){
  extern __shared__ __align__(16) u16 smem[];      // 135168 B dynamic
  float* sMax = (float*)(smem + 65536);            // byte 131072: [q 128][wk 4]
  float* sSum = sMax + 512;                        // byte 133120: [q 128][wk 4]
  const int wgid = blockIdx.x;                     // 0..511; XCD-chunked remap (512 % 8 == 0 -> bijective)
  const int orig = (wgid & 7)*64 + (wgid >> 3);
  const int b = orig >> 5, h = (orig >> 2) & 7, q0 = (orig & 3) * 128;
  const int bh = b*8 + h;
  const int tid = threadIdx.x, wv = tid>>6, lane = tid&63, g = lane>>4, r = lane&15;
  const int wq = wv>>2, wk = wv&3;
  const size_t base = (size_t)bh * 262144;
  const u16* Qb = Qt + base + (size_t)q0*512;
  const u16* Kb = Kt + base;
  const u16* Vb = Vh + base;

  // staging: chunk i = wv*5+j covers rows [i*16,i*16+16) of stacked [Q(128 rows); K(512 rows)],
  // each row 64B = 4 x 16B chunks; lane L: row = i*16 + (L>>2), phys chunk = L&3,
  // logical c-chunk = (L&3) ^ (row&3)  (source-side pre-swizzle).
  const u16* gsrc[5];
  int ldoff[5];
  {
    const int l4 = lane >> 2, pc = lane & 3;
#pragma unroll
    for (int j = 0; j < 5; ++j){
      const int i = wv*5 + j;
      const int row = ((i < 8) ? (i*16) : ((i-8)*16)) + l4;
      const u16* bp = (i < 8) ? (Qb + (size_t)row*512) : (Kb + (size_t)row*512);
      gsrc[j] = bp + ((pc ^ (row & 3)) * 8);
      ldoff[j] = i * 512;                          // u16 units; Q at [0,4096), K at [4096,20480)
    }
  }

  f32x4 s[4][8];
#pragma unroll
  for (int mt = 0; mt < 4; ++mt)
#pragma unroll
    for (int nt = 0; nt < 8; ++nt) s[mt][nt] = (f32x4){0.f,0.f,0.f,0.f};

  const int qswz = (g ^ (r & 3)) * 8;              // swizzled 16B-chunk offset within 64B row (u16)

#define STAGE_QK(bufbase, c0) do { \
    u16* _bb = (bufbase); \
    _Pragma("unroll") \
    for (int _j = 0; _j < 5; ++_j) gl_lds16(gsrc[_j] + (c0), _bb + ldoff[_j]); \
  } while(0)

#define QK_COMPUTE(bbp) do { \
    const u16* _cb = (bbp); \
    bf16x8 a_[4], kb_[8]; \
    _Pragma("unroll") \
    for (int _mt = 0; _mt < 4; ++_mt) a_[_mt] = *(const bf16x8*)&_cb[(wq*64 + _mt*16 + r)*32 + qswz]; \
    _Pragma("unroll") \
    for (int _nt = 0; _nt < 8; ++_nt) kb_[_nt] = *(const bf16x8*)&_cb[4096 + (wk*128 + _nt*16 + r)*32 + qswz]; \
    __builtin_amdgcn_s_setprio(1); \
    _Pragma("unroll") \
    for (int _mt = 0; _mt < 4; ++_mt) \
      _Pragma("unroll") \
      for (int _nt = 0; _nt < 8; ++_nt) s[_mt][_nt] = MFMA(a_[_mt], kb_[_nt], s[_mt][_nt]); \
    __builtin_amdgcn_s_setprio(0); \
  } while(0)

  // ---- Phase 1: S[q 128][k 512] = sum_c Q K^T, c-steps of 32, depth-2 pipeline over 3 buffers
  STAGE_QK(smem,         0);                       // cs=0 -> buf0
  STAGE_QK(smem + 20480, 32);                      // cs=1 -> buf1
  int bcur = 0;
  for (int cs = 0; cs < 15; ++cs){
    asm volatile("s_waitcnt vmcnt(5)" ::: "memory");   // own stage(cs) done; stage(cs+1) in flight
    __builtin_amdgcn_s_barrier();                      // all waves' stage(cs) visible; buf[(cs-1)%3] free
    __builtin_amdgcn_sched_barrier(0);
    if (cs < 14){
      int bn = bcur + 2; if (bn >= 3) bn -= 3;
      STAGE_QK(smem + bn*20480, (cs+2)*32);
    }
    QK_COMPUTE(smem + bcur*20480);
    if (++bcur == 3) bcur = 0;
  }
  asm volatile("s_waitcnt vmcnt(0)" ::: "memory");
  __builtin_amdgcn_s_barrier();
  __builtin_amdgcn_sched_barrier(0);
  QK_COMPUTE(smem + bcur*20480);                   // cs=15 (buf 0)

  // ---- softmax over k=512 (D layout: q = wq*64+mt*16+g*4+rr, k = wk*128+nt*16+r)
#pragma unroll
  for (int mt = 0; mt < 4; ++mt)
#pragma unroll
    for (int nt = 0; nt < 8; ++nt)
#pragma unroll
      for (int rr = 0; rr < 4; ++rr) s[mt][nt][rr] *= 0.125f;

  float mx[4][4];
#pragma unroll
  for (int mt = 0; mt < 4; ++mt)
#pragma unroll
    for (int rr = 0; rr < 4; ++rr){
      float m = s[mt][0][rr];
#pragma unroll
      for (int nt = 1; nt < 8; ++nt) m = fmaxf(m, s[mt][nt][rr]);
      m = fmaxf(m, __shfl_xor(m, 1, 64)); m = fmaxf(m, __shfl_xor(m, 2, 64));
      m = fmaxf(m, __shfl_xor(m, 4, 64)); m = fmaxf(m, __shfl_xor(m, 8, 64));
      mx[mt][rr] = m;
    }
  if (r == 0){
#pragma unroll
    for (int mt = 0; mt < 4; ++mt)
#pragma unroll
      for (int rr = 0; rr < 4; ++rr) sMax[(wq*64 + mt*16 + g*4 + rr)*4 + wk] = mx[mt][rr];
  }
  __syncthreads();
#pragma unroll
  for (int mt = 0; mt < 4; ++mt)
#pragma unroll
    for (int rr = 0; rr < 4; ++rr){
      float4 v = *(const float4*)&sMax[(wq*64 + mt*16 + g*4 + rr)*4];
      mx[mt][rr] = fmaxf(fmaxf(v.x, v.y), fmaxf(v.z, v.w));
    }
  float inv[4][4];
#pragma unroll
  for (int mt = 0; mt < 4; ++mt)
#pragma unroll
    for (int rr = 0; rr < 4; ++rr){
      float t = 0.f;
#pragma unroll
      for (int nt = 0; nt < 8; ++nt){
        float e = __expf(s[mt][nt][rr] - mx[mt][rr]);
        s[mt][nt][rr] = e; t += e;
      }
      t += __shfl_xor(t, 1, 64); t += __shfl_xor(t, 2, 64);
      t += __shfl_xor(t, 4, 64); t += __shfl_xor(t, 8, 64);
      inv[mt][rr] = t;                             // wave-partial sum for now
    }
  if (r == 0){
#pragma unroll
    for (int mt = 0; mt < 4; ++mt)
#pragma unroll
      for (int rr = 0; rr < 4; ++rr) sSum[(wq*64 + mt*16 + g*4 + rr)*4 + wk] = inv[mt][rr];
  }
  __syncthreads();
#pragma unroll
  for (int mt = 0; mt < 4; ++mt)
#pragma unroll
    for (int rr = 0; rr < 4; ++rr){
      float4 v = *(const float4*)&sSum[(wq*64 + mt*16 + g*4 + rr)*4];
      inv[mt][rr] = 1.f / (v.x + v.y + v.z + v.w);
    }
  // write P (bf16, chunk-swizzled ch^(q&7)) over the dead staging region
  {
    const int kx7 = r & 7, kbase = wk*16 + (r>>3);
#pragma unroll
    for (int mt = 0; mt < 4; ++mt)
#pragma unroll
      for (int rr = 0; rr < 4; ++rr){
        const int q = wq*64 + mt*16 + g*4 + rr;
        const int ro = q*512, qx = q & 7;
        const float iv = inv[mt][rr];
#pragma unroll
        for (int nt = 0; nt < 8; ++nt){
          const int ch = kbase + nt*2;             // k>>3
          smem[ro + ((ch ^ qx) * 8) + kx7] = f2bf(s[mt][nt][rr] * iv);
        }
      }
  }
  // early V prefetch: issue first fragments before the barrier so HBM latency hides under it
  const u16* Vw = Vb + (size_t)(wv*64 + r)*512 + g*8;
  bf16x8 vf[2][4];
#pragma unroll
  for (int mt = 0; mt < 4; ++mt) vf[0][mt] = *(const bf16x8*)(Vw + mt*8192);
  __syncthreads();

  // ---- Phase 2: A[c 512][q 128] = sum_k V[c][k] P[q][k]; wave owns c-range 64, barrier-free
  f32x4 o[4][8];
#pragma unroll
  for (int mt = 0; mt < 4; ++mt)
#pragma unroll
    for (int nt = 0; nt < 8; ++nt) o[mt][nt] = (f32x4){0.f,0.f,0.f,0.f};
#pragma unroll
  for (int kk = 0; kk < 16; ++kk){
    if (kk < 15){
#pragma unroll
      for (int mt = 0; mt < 4; ++mt) vf[(kk+1)&1][mt] = *(const bf16x8*)(Vw + mt*8192 + (kk+1)*32);
    }
    bf16x8 pp[8];
#pragma unroll
    for (int nt = 0; nt < 8; ++nt){
      const int q = nt*16 + r;
      pp[nt] = *(const bf16x8*)&smem[q*512 + (((kk*4 + g) ^ (r & 7)) * 8)];
    }
    __builtin_amdgcn_s_setprio(1);
#pragma unroll
    for (int mt = 0; mt < 4; ++mt)
#pragma unroll
      for (int nt = 0; nt < 8; ++nt) o[mt][nt] = MFMA(vf[kk&1][mt], pp[nt], o[mt][nt]);
    __builtin_amdgcn_s_setprio(0);
  }
  __syncthreads();                                  // all P reads done; reuse smem as At bounce

  // bounce o -> LDS [q][c] (same chunk swizzle), then coalesced copy out
#pragma unroll
  for (int mt = 0; mt < 4; ++mt){
    const int c = wv*64 + mt*16 + g*4;
    const int ch = c >> 3, cl = c & 7;
#pragma unroll
    for (int nt = 0; nt < 8; ++nt){
      const int q = nt*16 + r;
      bf16x4 pk;
#pragma unroll
      for (int rr = 0; rr < 4; ++rr) pk[rr] = (short)f2bf(o[mt][nt][rr]);
      *(bf16x4*)&smem[q*512 + ((ch ^ (r & 7)) * 8) + cl] = pk;
    }
  }
  __syncthreads();
  u16* Ad = At + ((size_t)(bh*512 + q0))*512;      // exactly this block's Q rows (in-place alias)
#pragma unroll
  for (int i = 0; i < 16; ++i){
    const int idx = tid + i*512, q = idx >> 6, ch = idx & 63;
    bf16x8 d = *(const bf16x8*)&smem[q*512 + ((ch ^ (q & 7)) * 8)];
    *(bf16x8*)(Ad + (size_t)q*512 + ch*8) = d;
  }
#undef STAGE_QK
#undef QK_COMPUTE
}

// ---------------- Kernel 5: proj GEMM (m97-style) + f32 residual -> f32 out ----------------
__global__ __launch_bounds__(256,2) void k_proj(const u16* __restrict__ At, const u16* __restrict__ wp,
                                                const float* __restrict__ bpr, const float* __restrict__ x,
                                                float* __restrict__ out){
  __shared__ u16 smem[17408];
  u16* sA = smem;
  u16* sW = smem + 8192;
  const int l0 = blockIdx.x*128, o0 = blockIdx.y*128, b = blockIdx.z;
  const int tid = threadIdx.x, wv = tid>>6, lane = tid&63, g = lane>>4, r = lane&15;
  const int wm = wv>>1, wn = wv&1;
  const u16* Ab = At + ((size_t)(b*4096 + l0))*512;
  const u16* Wb = wp + (size_t)o0*512;
  int srow[4], scol[4];
#pragma unroll
  for (int j = 0; j < 4; ++j){
    int s = wv*256 + j*64 + lane;
    srow[j] = s >> 3;
    scol[j] = ((s & 7) ^ (srow[j] & 7)) * 8;
  }
  f32x4 acc[4][4];
#pragma unroll
  for (int mt = 0; mt < 4; ++mt)
#pragma unroll
    for (int nt = 0; nt < 4; ++nt) acc[mt][nt] = (f32x4){0.f,0.f,0.f,0.f};
  const int key = r & 7;
  for (int c0 = 0; c0 < 512; c0 += 64){
    __syncthreads();
#pragma unroll
    for (int j = 0; j < 4; ++j){
      u16* ldst = &smem[(wv*256 + j*64)*8];
      gl_lds16(Ab + (size_t)srow[j]*512 + c0 + scol[j], ldst);
      gl_lds16(Wb + (size_t)srow[j]*512 + c0 + scol[j], ldst + 8192);
    }
    __syncthreads();
#pragma unroll
    for (int half = 0; half < 2; ++half){
      bf16x8 a[4], w[4];
#pragma unroll
      for (int mt = 0; mt < 4; ++mt){ int R = wm*64 + mt*16 + r; a[mt] = *(const bf16x8*)&sA[(R*8 + ((half*4+g) ^ key))*8]; }
#pragma unroll
      for (int nt = 0; nt < 4; ++nt){ int R = wn*64 + nt*16 + r; w[nt] = *(const bf16x8*)&sW[(R*8 + ((half*4+g) ^ key))*8]; }
#pragma unroll
      for (int mt = 0; mt < 4; ++mt)
#pragma unroll
        for (int nt = 0; nt < 4; ++nt) acc[mt][nt] = MFMA(a[mt], w[nt], acc[mt][nt]);
    }
  }
  __syncthreads();
#pragma unroll
  for (int nt = 0; nt < 4; ++nt){
    const int ol = wn*64 + nt*16 + r;
    const float bi = bpr[o0 + ol];
#pragma unroll
    for (int mt = 0; mt < 4; ++mt){
      const int ll = wm*64 + mt*16 + g*4;
      bf16x4 pk;
#pragma unroll
      for (int rr = 0; rr < 4; ++rr) pk[rr] = (short)f2bf(acc[mt][nt][rr] + bi);
      *(bf16x4*)&smem[ol*136 + ll] = pk;            // LDS [o][l]
    }
  }
  __syncthreads();
#pragma unroll
  for (int i = 0; i < 16; ++i){
    int v = tid + i*256; int row = v >> 5, seg = v & 31;   // row=o-local 0..127, seg*4 = l-local
    bf16x4 d = *(const bf16x4*)&smem[row*136 + seg*4];
    const size_t gi = ((size_t)(b*512 + o0 + row))*4096 + l0 + seg*4;
    float4 xv = *(const float4*)(x + gi);
    float4 ov;
    ov.x = bf2f((u16)d[0]) + xv.x;
    ov.y = bf2f((u16)d[1]) + xv.y;
    ov.z = bf2f((u16)d[2]) + xv.z;
    ov.w = bf2f((u16)d[3]) + xv.w;
    *(float4*)(out + gi) = ov;
  }
}

extern "C" void kernel_launch(void* const* d_in, const int* in_sizes, int n_in,
                              void* d_out, int out_size, void* d_ws, size_t ws_size,
                              hipStream_t stream) {
  (void)in_sizes; (void)n_in; (void)out_size; (void)ws_size;
  const float* x     = (const float*)d_in[0];
  const float* gamma = (const float*)d_in[1];
  const float* beta  = (const float*)d_in[2];
  const float* wqkv  = (const float*)d_in[3];
  const float* bqkv  = (const float*)d_in[4];
  const float* wproj = (const float*)d_in[5];
  const float* bproj = (const float*)d_in[6];
  float* out = (float*)d_out;
  char* ws = (char*)d_ws;

  float* stats = (float*)ws;                        // 8 KB
  u16* W16  = (u16*)(ws + 8192);                    // wqkv16 (786432) + wproj16 (262144)
  u16* Wq16 = W16;
  u16* Wp16 = W16 + 786432;
  u16* Qt = (u16*)(ws + 8192 + 2097152);            // 64 MiB  [b][h][pos][c]  (becomes At in place)
  u16* Kt = Qt + (size_t)33554432;                  // 64 MiB  [b][h][pos][c]
  u16* Vh = Kt + (size_t)33554432;                  // 64 MiB  [b][h][c][pos]
  u16* At = Qt;                                     // in-place alias (see k_attn)
  u16* Xnt = (u16*)d_out;                           // bf16 staging in d_out (dead before k_proj writes)

  static bool attn_attr = false;
  if (!attn_attr){
    hipFuncSetAttribute((const void*)k_attn, hipFuncAttributeMaxDynamicSharedMemorySize, 135168);
    attn_attr = true;
  }

  k_gn_stats<<<512, 256, 0, stream>>>(x, stats);
  k_conv_w<<<1024, 256, 0, stream>>>(wqkv, wproj, W16);
  k_gn_t<<<dim3(64,8,16), 256, 0, stream>>>(x, stats, gamma, beta, Xnt);
  k_qkv<<<dim3(32,12,16), 256, 0, stream>>>(Xnt, Wq16, bqkv, Qt, Kt, Vh);
  k_attn<<<512, 512, 135168, stream>>>(Qt, Kt, Vh, At);
  k_proj<<<dim3(32,4,16), 256, 0, stream>>>(At, Wp16, bproj, x, out);
}